// Round 4
// baseline (116.920 us; speedup 1.0000x reference)
//
#include <hip/hip_runtime.h>

// EncoderRNN: 1-token, batch-1, bidirectional 2-layer LSTM. H=2048, EMB=1024.
// Memory-bound: 604 MB of fp32 weights read once (~91 us at 6.3 TB/s).
// TWO kernels (one stream barrier, no cooperative launch):
//   K1: L0 gates (Wih0*x + Whh0*h0 + biases) -> gates0[2][8192]
//       plus L1 recurrent partial (Whh1*h0 + biases) -> part1[2][8192]
//   K2: every block redundantly recomputes cell0 from gates0 (64 KB, L2/L3
//       resident) into LDS x1[4096]; block 0 also writes h_n/c_n rows 0,1.
//       Then each wave computes the 4 gate rows {j,H+j,2H+j,3H+j} of one
//       (dir,unit) of layer 1 (Wih1 . x1 + part1) and applies the cell
//       inline -> output, h_n/c_n rows 2,3.

#define HID 2048
#define G4H 8192

__device__ __forceinline__ float wave_reduce_sum(float v) {
    #pragma unroll
    for (int off = 32; off > 0; off >>= 1)
        v += __shfl_down(v, off, 64);
    return v;
}
__device__ __forceinline__ float sigmoidf_(float v) { return 1.f / (1.f + expf(-v)); }

// ---------------- K1: 32768 waves -> 8192 blocks x 256 ----------------
__global__ __launch_bounds__(256) void k1_gates0_part1(
    const int*   __restrict__ tok,
    const float* __restrict__ emb,    // [VOCAB][1024]
    const float* __restrict__ Wih0,   // [2][8192][1024]
    const float* __restrict__ Whh0,   // [2][8192][2048]
    const float* __restrict__ bih0,   // [2][8192]
    const float* __restrict__ bhh0,
    const float* __restrict__ Whh1,   // [2][8192][2048]
    const float* __restrict__ bih1,
    const float* __restrict__ bhh1,
    const float* __restrict__ h0,     // [4][2048]
    float* __restrict__ gates0,       // ws [2][8192]
    float* __restrict__ part1)        // ws [2][8192]
{
    const int wave = (int)((blockIdx.x * blockDim.x + threadIdx.x) >> 6);
    const int lane = (int)(threadIdx.x & 63);

    if (wave < 2 * G4H) {
        const int dir = wave >> 13;
        const int r   = wave & (G4H - 1);
        const float*  x   = emb + (size_t)tok[0] * 1024;
        const float4* wih = (const float4*)(Wih0 + ((size_t)dir * G4H + r) * 1024);
        const float4* whh = (const float4*)(Whh0 + ((size_t)dir * G4H + r) * HID);
        const float4* xv  = (const float4*)x;
        const float4* hv  = (const float4*)(h0 + (size_t)dir * HID);

        float acc = 0.f;
        #pragma unroll
        for (int i = 0; i < 1024 / 4 / 64; ++i) {
            float4 w = wih[lane + i * 64], b = xv[lane + i * 64];
            acc += w.x * b.x + w.y * b.y + w.z * b.z + w.w * b.w;
        }
        #pragma unroll
        for (int i = 0; i < HID / 4 / 64; ++i) {
            float4 w = whh[lane + i * 64], b = hv[lane + i * 64];
            acc += w.x * b.x + w.y * b.y + w.z * b.z + w.w * b.w;
        }
        acc = wave_reduce_sum(acc);
        if (lane == 0) {
            int row = dir * G4H + r;
            gates0[row] = acc + bih0[row] + bhh0[row];
        }
    } else {
        const int w2  = wave - 2 * G4H;
        const int dir = w2 >> 13;
        const int r   = w2 & (G4H - 1);
        const float4* whh = (const float4*)(Whh1 + ((size_t)dir * G4H + r) * HID);
        const float4* hv  = (const float4*)(h0 + (size_t)(2 + dir) * HID);

        float acc = 0.f;
        #pragma unroll
        for (int i = 0; i < HID / 4 / 64; ++i) {
            float4 w = whh[lane + i * 64], b = hv[lane + i * 64];
            acc += w.x * b.x + w.y * b.y + w.z * b.z + w.w * b.w;
        }
        acc = wave_reduce_sum(acc);
        if (lane == 0) {
            int row = dir * G4H + r;
            part1[row] = acc + bih1[row] + bhh1[row];
        }
    }
}

// ---------------- K2: 4096 waves -> 1024 blocks x 256 ----------------
__global__ __launch_bounds__(256) void k2_layer1(
    const float* __restrict__ gates0, // ws [2][8192]
    const float* __restrict__ part1,  // ws [2][8192]
    const float* __restrict__ Wih1,   // [2][8192][4096]
    const float* __restrict__ c0,     // [4][2048]
    float* __restrict__ out)          // [4096 output | 8192 h_n | 8192 c_n]
{
    __shared__ float x1[2 * HID];     // 16 KB

    // Stage 1: redundant cell0 (16 units per thread, coalesced within gate segs)
    #pragma unroll
    for (int k = 0; k < 16; ++k) {
        const int idx = k * 256 + (int)threadIdx.x;   // 0..4095
        const int dir = idx >> 11;
        const int j   = idx & (HID - 1);
        const float* g = gates0 + dir * G4H;
        float gi = g[j];
        float gf = g[HID + j];
        float gg = g[2 * HID + j];
        float go = g[3 * HID + j];
        float cp = c0[(size_t)dir * HID + j];
        float c2 = sigmoidf_(gf) * cp + sigmoidf_(gi) * tanhf(gg);
        float h2 = sigmoidf_(go) * tanhf(c2);
        x1[idx] = h2;
        if (blockIdx.x == 0) {
            out[4096  + (size_t)dir * HID + j] = h2;   // h_n rows 0,1
            out[12288 + (size_t)dir * HID + j] = c2;   // c_n rows 0,1
        }
    }
    __syncthreads();

    // Stage 2: one (dir,j) per wave; 4 gate rows; inline cell1
    const int wave = (int)((blockIdx.x * blockDim.x + threadIdx.x) >> 6); // 0..4095
    const int lane = (int)(threadIdx.x & 63);
    const int dir  = wave >> 11;
    const int j    = wave & (HID - 1);

    const float4* xv = (const float4*)x1;
    float acc[4] = {0.f, 0.f, 0.f, 0.f};
    #pragma unroll
    for (int g = 0; g < 4; ++g) {
        const float4* wih = (const float4*)(Wih1 + ((size_t)dir * G4H + g * HID + j) * 4096);
        #pragma unroll 4
        for (int i = 0; i < 4096 / 4 / 64; ++i) {
            float4 w = wih[lane + i * 64], b = xv[lane + i * 64];
            acc[g] += w.x * b.x + w.y * b.y + w.z * b.z + w.w * b.w;
        }
    }
    #pragma unroll
    for (int g = 0; g < 4; ++g) acc[g] = wave_reduce_sum(acc[g]);

    if (lane == 0) {
        const int rb = dir * G4H + j;
        float gi = acc[0] + part1[rb];
        float gf = acc[1] + part1[rb + HID];
        float gg = acc[2] + part1[rb + 2 * HID];
        float go = acc[3] + part1[rb + 3 * HID];
        float cp = c0[(size_t)(2 + dir) * HID + j];
        float c2 = sigmoidf_(gf) * cp + sigmoidf_(gi) * tanhf(gg);
        float h2 = sigmoidf_(go) * tanhf(c2);
        out[4096  + (size_t)(2 + dir) * HID + j] = h2;  // h_n rows 2,3
        out[12288 + (size_t)(2 + dir) * HID + j] = c2;  // c_n rows 2,3
        out[(size_t)dir * HID + j] = h2;                // output [hf, hb]
    }
}

extern "C" void kernel_launch(void* const* d_in, const int* in_sizes, int n_in,
                              void* d_out, int out_size, void* d_ws, size_t ws_size,
                              hipStream_t stream) {
    const int*   ids  = (const int*)  d_in[0];
    const float* h0   = (const float*)d_in[1];
    const float* c0   = (const float*)d_in[2];
    const float* emb  = (const float*)d_in[3];
    const float* Wih0 = (const float*)d_in[4];
    const float* Whh0 = (const float*)d_in[5];
    const float* bih0 = (const float*)d_in[6];
    const float* bhh0 = (const float*)d_in[7];
    const float* Wih1 = (const float*)d_in[8];
    const float* Whh1 = (const float*)d_in[9];
    const float* bih1 = (const float*)d_in[10];
    const float* bhh1 = (const float*)d_in[11];

    float* out    = (float*)d_out;
    float* gates0 = (float*)d_ws;          // [2][8192]
    float* part1  = gates0 + 2 * G4H;      // [2][8192]

    k1_gates0_part1<<<8192, 256, 0, stream>>>(ids, emb, Wih0, Whh0, bih0, bhh0,
                                              Whh1, bih1, bhh1, h0, gates0, part1);
    k2_layer1<<<1024, 256, 0, stream>>>(gates0, part1, Wih1, c0, out);
}

// Round 5
// 107.140 us; speedup vs baseline: 1.0913x; 1.0913x over previous
//
#include <hip/hip_runtime.h>

// EncoderRNN: 1-token, batch-1, bidirectional 2-layer LSTM. H=2048, EMB=1024.
// Memory-bound: 604 MB fp32 weights read once (~91 us at 6.3 TB/s read BW).
// TWO kernels, no tiny cell dispatches, no redundant recompute:
//   K1 blocks 0..4095:    block=(dir,j) owns L0 gate rows {j,H+j,2H+j,3H+j};
//                         4 waves x 1 row each (Wih0*x + Whh0*h0), LDS reduce,
//                         thread 0 applies cell0 -> x1, h_n/c_n rows 0,1.
//      blocks 4096..8191: L1 recurrent partial, 1 row/wave ->
//                         part1 = Whh1*h0 + bih1 + bhh1.
//   K2 block=(dir,j):     4 waves x 1 row of Wih1 (16KB) . x1, LDS reduce,
//                         thread 0 applies cell1 -> output, h_n/c_n rows 2,3.
// Row-per-wave is kept at 1 everywhere: 64 waves/CU is what keeps enough
// loads in flight to saturate HBM (R3's 4-rows/wave starved it).

#define HID 2048
#define G4H 8192

__device__ __forceinline__ float wave_reduce_sum(float v) {
    #pragma unroll
    for (int off = 32; off > 0; off >>= 1)
        v += __shfl_down(v, off, 64);
    return v;
}
__device__ __forceinline__ float sigmoidf_(float v) { return 1.f / (1.f + expf(-v)); }

__device__ __forceinline__ float dot_row(const float4* __restrict__ w,
                                         const float4* __restrict__ v,
                                         int lane, int n4) {
    float acc = 0.f;
    #pragma unroll 8
    for (int i = 0; i < n4; ++i) {
        float4 a = w[lane + i * 64], b = v[lane + i * 64];
        acc += a.x * b.x + a.y * b.y + a.z * b.z + a.w * b.w;
    }
    return acc;
}

// ---------------- K1: 8192 blocks x 256 ----------------
__global__ __launch_bounds__(256) void k1_l0cell_part1(
    const int*   __restrict__ tok,
    const float* __restrict__ emb,    // [VOCAB][1024]
    const float* __restrict__ Wih0,   // [2][8192][1024]
    const float* __restrict__ Whh0,   // [2][8192][2048]
    const float* __restrict__ bih0,   // [2][8192]
    const float* __restrict__ bhh0,
    const float* __restrict__ Whh1,   // [2][8192][2048]
    const float* __restrict__ bih1,
    const float* __restrict__ bhh1,
    const float* __restrict__ h0,     // [4][2048]
    const float* __restrict__ c0,     // [4][2048]
    float* __restrict__ out,          // [4096 out | 8192 h_n | 8192 c_n]
    float* __restrict__ x1,           // ws [4096]
    float* __restrict__ part1)        // ws [2][8192]
{
    const int lane = (int)(threadIdx.x & 63);
    const int w    = (int)(threadIdx.x >> 6);      // wave in block: 0..3
    const int bid  = (int)blockIdx.x;

    if (bid < 4096) {
        // ---- L0 cell block: (dir, j), wave w = gate w's row ----
        __shared__ float gsum[4];
        const int dir = bid >> 11;
        const int j   = bid & (HID - 1);
        const int row = dir * G4H + w * HID + j;

        const float* x = emb + (size_t)tok[0] * 1024;
        float acc = dot_row((const float4*)(Wih0 + (size_t)row * 1024),
                            (const float4*)x, lane, 1024 / 256);
        acc += dot_row((const float4*)(Whh0 + (size_t)row * HID),
                       (const float4*)(h0 + (size_t)dir * HID), lane, HID / 256);
        acc = wave_reduce_sum(acc);
        if (lane == 0) gsum[w] = acc + bih0[row] + bhh0[row];
        __syncthreads();
        if (threadIdx.x == 0) {
            float gi = gsum[0], gf = gsum[1], gg = gsum[2], go = gsum[3];
            float cp = c0[(size_t)dir * HID + j];
            float c2 = sigmoidf_(gf) * cp + sigmoidf_(gi) * tanhf(gg);
            float h2 = sigmoidf_(go) * tanhf(c2);
            x1[(size_t)dir * HID + j] = h2;
            out[4096  + (size_t)dir * HID + j] = h2;   // h_n rows 0,1
            out[12288 + (size_t)dir * HID + j] = c2;   // c_n rows 0,1
        }
    } else {
        // ---- L1 recurrent partial: 1 row per wave ----
        const int widx = (bid - 4096) * 4 + w;         // 0..16383
        const int dir  = widx >> 13;
        const int r    = widx & (G4H - 1);
        const int row  = dir * G4H + r;
        float acc = dot_row((const float4*)(Whh1 + (size_t)row * HID),
                            (const float4*)(h0 + (size_t)(2 + dir) * HID),
                            lane, HID / 256);
        acc = wave_reduce_sum(acc);
        if (lane == 0) part1[row] = acc + bih1[row] + bhh1[row];
    }
}

// ---------------- K2: 4096 blocks x 256 ----------------
__global__ __launch_bounds__(256) void k2_l1cell(
    const float* __restrict__ x1,     // ws [4096]
    const float* __restrict__ part1,  // ws [2][8192]
    const float* __restrict__ Wih1,   // [2][8192][4096]
    const float* __restrict__ c0,     // [4][2048]
    float* __restrict__ out)          // [4096 out | 8192 h_n | 8192 c_n]
{
    __shared__ float gsum[4];
    const int lane = (int)(threadIdx.x & 63);
    const int w    = (int)(threadIdx.x >> 6);
    const int bid  = (int)blockIdx.x;
    const int dir  = bid >> 11;
    const int j    = bid & (HID - 1);
    const int row  = dir * G4H + w * HID + j;

    float acc = dot_row((const float4*)(Wih1 + (size_t)row * 4096),
                        (const float4*)x1, lane, 4096 / 256);
    acc = wave_reduce_sum(acc);
    if (lane == 0) gsum[w] = acc + part1[row];
    __syncthreads();
    if (threadIdx.x == 0) {
        float gi = gsum[0], gf = gsum[1], gg = gsum[2], go = gsum[3];
        float cp = c0[(size_t)(2 + dir) * HID + j];
        float c2 = sigmoidf_(gf) * cp + sigmoidf_(gi) * tanhf(gg);
        float h2 = sigmoidf_(go) * tanhf(c2);
        out[4096  + (size_t)(2 + dir) * HID + j] = h2;  // h_n rows 2,3
        out[12288 + (size_t)(2 + dir) * HID + j] = c2;  // c_n rows 2,3
        out[(size_t)dir * HID + j] = h2;                // output [hf, hb]
    }
}

extern "C" void kernel_launch(void* const* d_in, const int* in_sizes, int n_in,
                              void* d_out, int out_size, void* d_ws, size_t ws_size,
                              hipStream_t stream) {
    const int*   ids  = (const int*)  d_in[0];
    const float* h0   = (const float*)d_in[1];
    const float* c0   = (const float*)d_in[2];
    const float* emb  = (const float*)d_in[3];
    const float* Wih0 = (const float*)d_in[4];
    const float* Whh0 = (const float*)d_in[5];
    const float* bih0 = (const float*)d_in[6];
    const float* bhh0 = (const float*)d_in[7];
    const float* Wih1 = (const float*)d_in[8];
    const float* Whh1 = (const float*)d_in[9];
    const float* bih1 = (const float*)d_in[10];
    const float* bhh1 = (const float*)d_in[11];

    float* out   = (float*)d_out;
    float* part1 = (float*)d_ws;           // [2][8192]
    float* x1    = part1 + 2 * G4H;        // [4096]

    k1_l0cell_part1<<<8192, 256, 0, stream>>>(ids, emb, Wih0, Whh0, bih0, bhh0,
                                              Whh1, bih1, bhh1, h0, c0,
                                              out, x1, part1);
    k2_l1cell<<<4096, 256, 0, stream>>>(x1, part1, Wih1, c0, out);
}

// Round 6
// 96.051 us; speedup vs baseline: 1.2173x; 1.1154x over previous
//
#include <hip/hip_runtime.h>

// EncoderRNN: 1-token, batch-1, bidirectional 2-layer LSTM. H=2048, EMB=1024.
// Memory-bound: 604 MiB fp32 weights read once (~100 us at 6.3 TB/s read BW).
// Structure identical to R4 (2 dispatches, cell fused via 4-waves-per-unit
// blocks in K1a/K2, 1 row/wave everywhere). NEW in R5: weight streams use
// non-temporal loads (read-once data; avoid L2 allocation/pollution). The
// small reused vectors (emb row, h0, x1) stay cached.

#define HID 2048
#define G4H 8192

typedef float f4 __attribute__((ext_vector_type(4)));

__device__ __forceinline__ float wave_reduce_sum(float v) {
    #pragma unroll
    for (int off = 32; off > 0; off >>= 1)
        v += __shfl_down(v, off, 64);
    return v;
}
__device__ __forceinline__ float sigmoidf_(float v) { return 1.f / (1.f + expf(-v)); }

// dot of one weight row (non-temporal, read-once) with a cached vector
__device__ __forceinline__ float dot_row_nt(const f4* __restrict__ w,
                                            const f4* __restrict__ v,
                                            int lane, int n4) {
    float acc = 0.f;
    #pragma unroll 8
    for (int i = 0; i < n4; ++i) {
        f4 a = __builtin_nontemporal_load(w + lane + i * 64);
        f4 b = v[lane + i * 64];
        acc += a.x * b.x + a.y * b.y + a.z * b.z + a.w * b.w;
    }
    return acc;
}

// ---------------- K1: 8192 blocks x 256 ----------------
__global__ __launch_bounds__(256) void k1_l0cell_part1(
    const int*   __restrict__ tok,
    const float* __restrict__ emb,    // [VOCAB][1024]
    const float* __restrict__ Wih0,   // [2][8192][1024]
    const float* __restrict__ Whh0,   // [2][8192][2048]
    const float* __restrict__ bih0,   // [2][8192]
    const float* __restrict__ bhh0,
    const float* __restrict__ Whh1,   // [2][8192][2048]
    const float* __restrict__ bih1,
    const float* __restrict__ bhh1,
    const float* __restrict__ h0,     // [4][2048]
    const float* __restrict__ c0,     // [4][2048]
    float* __restrict__ out,          // [4096 out | 8192 h_n | 8192 c_n]
    float* __restrict__ x1,           // ws [4096]
    float* __restrict__ part1)        // ws [2][8192]
{
    const int lane = (int)(threadIdx.x & 63);
    const int w    = (int)(threadIdx.x >> 6);      // wave in block: 0..3
    const int bid  = (int)blockIdx.x;

    if (bid < 4096) {
        // ---- L0 cell block: (dir, j), wave w = gate w's row ----
        __shared__ float gsum[4];
        const int dir = bid >> 11;
        const int j   = bid & (HID - 1);
        const int row = dir * G4H + w * HID + j;

        const float* x = emb + (size_t)tok[0] * 1024;
        float acc = dot_row_nt((const f4*)(Wih0 + (size_t)row * 1024),
                               (const f4*)x, lane, 1024 / 256);
        acc += dot_row_nt((const f4*)(Whh0 + (size_t)row * HID),
                          (const f4*)(h0 + (size_t)dir * HID), lane, HID / 256);
        acc = wave_reduce_sum(acc);
        if (lane == 0) gsum[w] = acc + bih0[row] + bhh0[row];
        __syncthreads();
        if (threadIdx.x == 0) {
            float gi = gsum[0], gf = gsum[1], gg = gsum[2], go = gsum[3];
            float cp = c0[(size_t)dir * HID + j];
            float c2 = sigmoidf_(gf) * cp + sigmoidf_(gi) * tanhf(gg);
            float h2 = sigmoidf_(go) * tanhf(c2);
            x1[(size_t)dir * HID + j] = h2;
            out[4096  + (size_t)dir * HID + j] = h2;   // h_n rows 0,1
            out[12288 + (size_t)dir * HID + j] = c2;   // c_n rows 0,1
        }
    } else {
        // ---- L1 recurrent partial: 1 row per wave ----
        const int widx = (bid - 4096) * 4 + w;         // 0..16383
        const int dir  = widx >> 13;
        const int r    = widx & (G4H - 1);
        const int row  = dir * G4H + r;
        float acc = dot_row_nt((const f4*)(Whh1 + (size_t)row * HID),
                               (const f4*)(h0 + (size_t)(2 + dir) * HID),
                               lane, HID / 256);
        acc = wave_reduce_sum(acc);
        if (lane == 0) part1[row] = acc + bih1[row] + bhh1[row];
    }
}

// ---------------- K2: 4096 blocks x 256 ----------------
__global__ __launch_bounds__(256) void k2_l1cell(
    const float* __restrict__ x1,     // ws [4096]
    const float* __restrict__ part1,  // ws [2][8192]
    const float* __restrict__ Wih1,   // [2][8192][4096]
    const float* __restrict__ c0,     // [4][2048]
    float* __restrict__ out)          // [4096 out | 8192 h_n | 8192 c_n]
{
    __shared__ float gsum[4];
    const int lane = (int)(threadIdx.x & 63);
    const int w    = (int)(threadIdx.x >> 6);
    const int bid  = (int)blockIdx.x;
    const int dir  = bid >> 11;
    const int j    = bid & (HID - 1);
    const int row  = dir * G4H + w * HID + j;

    float acc = dot_row_nt((const f4*)(Wih1 + (size_t)row * 4096),
                           (const f4*)x1, lane, 4096 / 256);
    acc = wave_reduce_sum(acc);
    if (lane == 0) gsum[w] = acc + part1[row];
    __syncthreads();
    if (threadIdx.x == 0) {
        float gi = gsum[0], gf = gsum[1], gg = gsum[2], go = gsum[3];
        float cp = c0[(size_t)(2 + dir) * HID + j];
        float c2 = sigmoidf_(gf) * cp + sigmoidf_(gi) * tanhf(gg);
        float h2 = sigmoidf_(go) * tanhf(c2);
        out[4096  + (size_t)(2 + dir) * HID + j] = h2;  // h_n rows 2,3
        out[12288 + (size_t)(2 + dir) * HID + j] = c2;  // c_n rows 2,3
        out[(size_t)dir * HID + j] = h2;                // output [hf, hb]
    }
}

extern "C" void kernel_launch(void* const* d_in, const int* in_sizes, int n_in,
                              void* d_out, int out_size, void* d_ws, size_t ws_size,
                              hipStream_t stream) {
    const int*   ids  = (const int*)  d_in[0];
    const float* h0   = (const float*)d_in[1];
    const float* c0   = (const float*)d_in[2];
    const float* emb  = (const float*)d_in[3];
    const float* Wih0 = (const float*)d_in[4];
    const float* Whh0 = (const float*)d_in[5];
    const float* bih0 = (const float*)d_in[6];
    const float* bhh0 = (const float*)d_in[7];
    const float* Wih1 = (const float*)d_in[8];
    const float* Whh1 = (const float*)d_in[9];
    const float* bih1 = (const float*)d_in[10];
    const float* bhh1 = (const float*)d_in[11];

    float* out   = (float*)d_out;
    float* part1 = (float*)d_ws;           // [2][8192]
    float* x1    = part1 + 2 * G4H;        // [4096]

    k1_l0cell_part1<<<8192, 256, 0, stream>>>(ids, emb, Wih0, Whh0, bih0, bhh0,
                                              Whh1, bih1, bhh1, h0, c0,
                                              out, x1, part1);
    k2_l1cell<<<4096, 256, 0, stream>>>(x1, part1, Wih1, c0, out);
}